// Round 4
// baseline (1059.976 us; speedup 1.0000x reference)
//
#include <hip/hip_runtime.h>

// AttentionBlock fused single-kernel (persistent, grid==capacity):
// B=8, C=128, H=W=128, GROUPS=8, HEADS=8, HEAD_DIM=16
// grid = 1024 blocks (= 256 CU x 4 blocks/CU, guaranteed by launch_bounds(256,4):
// VGPR<=128, LDS 34.9KB<=40KB) -> software grid barriers are safe.
// Phases: P0 stage x->LDS bf16 (swizzled) + GN stats | GS | P1(8 blks) fold GN->Asb,vA
// | GS | P2 GEMM1 + scores->Sg atomics | GS | P3(8 blks) softmax+w_eff | GS |
// P4 h^T->LDS, GEMM2, +b_out +x epilogue.
// LDS swizzle: element (row,col) at row*128 + (((col>>3) ^ (row&15))<<3) + (col&7)
// -> ds_write_b128 staging and ds_read_b128 fragments both at conflict floor.

#define NPOS 16384

typedef short short8 __attribute__((ext_vector_type(8)));   // 8 bf16
typedef float f32x4 __attribute__((ext_vector_type(4)));

__device__ __forceinline__ unsigned short f2bf(float f) {
    union { float f; unsigned u; } v; v.f = f;
    unsigned r = (v.u + 0x7fffu + ((v.u >> 16) & 1u)) >> 16;
    return (unsigned short)r;
}
__device__ __forceinline__ float bf2f(unsigned short h) {
    union { unsigned u; float f; } v; v.u = ((unsigned)h) << 16;
    return v.f;
}

// device-scope grid barrier; each counter used exactly once per launch (memset-zeroed)
__device__ __forceinline__ void gsync(unsigned* c, unsigned target) {
    __threadfence();
    __syncthreads();
    if (threadIdx.x == 0) {
        __hip_atomic_fetch_add(c, 1u, __ATOMIC_RELEASE, __HIP_MEMORY_SCOPE_AGENT);
        while (__hip_atomic_load(c, __ATOMIC_ACQUIRE, __HIP_MEMORY_SCOPE_AGENT) < target)
            __builtin_amdgcn_s_sleep(2);
    }
    __syncthreads();
}

__global__ __launch_bounds__(256, 4) void k_fused(
    const float* __restrict__ x,
    const float* __restrict__ gn_w, const float* __restrict__ gn_b,
    const float* __restrict__ w_in, const float* __restrict__ b_in,
    const float* __restrict__ w_out, const float* __restrict__ b_out,
    float* __restrict__ out,
    unsigned* __restrict__ ctr, float* __restrict__ stats,
    float* __restrict__ Sg, float* __restrict__ vA,
    unsigned short* __restrict__ Asb, unsigned short* __restrict__ weffb)
{
    __shared__ unsigned short Xt[16384];   // 32 KB, multi-purpose
    __shared__ float v_s[128];
    __shared__ float bo_s[128];
    __shared__ float ssv[128], tlv[128];
    __shared__ float gsum[16];

    const int t = threadIdx.x;
    const int lane = t & 63, wv = t >> 6;
    const int q = lane >> 4, i16 = lane & 15;
    const int b = blockIdx.x >> 7;
    const int tile = blockIdx.x & 127;
    const int p0 = tile << 7;
    const unsigned nblk = gridDim.x;
    const float* xb = x + (size_t)b * (128 * NPOS) + p0;

    // ---------- P0: stage x tile (bf16, swizzled [p][k]) + group stats ----------
    if (t < 16) gsum[t] = 0.f;
    __syncthreads();
    {
        const int p = t & 127;
        const int rowbase = p * 128;
        const int sw = p & 15;
#pragma unroll
        for (int m = 0; m < 8; ++m) {            // iteration m covers group m
            int jb = 2 * m + (t >> 7);           // 8-channel block index
            const float* col = xb + (size_t)(jb * 8) * NPOS + p;
            short8 o;
            float a1 = 0.f, a2 = 0.f;
#pragma unroll
            for (int e = 0; e < 8; ++e) {
                float f = col[(size_t)e * NPOS];
                a1 += f; a2 += f * f;
                ((unsigned short*)&o)[e] = f2bf(f);
            }
            *(short8*)&Xt[rowbase + ((jb ^ sw) << 3)] = o;
#pragma unroll
            for (int off = 32; off; off >>= 1) {
                a1 += __shfl_down(a1, off);
                a2 += __shfl_down(a2, off);
            }
            if (lane == 0) { atomicAdd(&gsum[m * 2], a1); atomicAdd(&gsum[m * 2 + 1], a2); }
        }
    }
    __syncthreads();
    if (t < 8) {
        atomicAdd(&stats[(b * 8 + t) * 2 + 0], gsum[t * 2]);
        atomicAdd(&stats[(b * 8 + t) * 2 + 1], gsum[t * 2 + 1]);
    }
    gsync(ctr + 0, nblk);

    // ---------- P1 (tile==0 only): fold GN -> Asb(bf16), vA ----------
    if (tile == 0) {
        if (t < 128) {
            int g = t >> 4;
            float s1 = stats[(b * 8 + g) * 2 + 0];
            float s2 = stats[(b * 8 + g) * 2 + 1];
            const float invN = 1.0f / 262144.0f;
            float mean = s1 * invN;
            float var = s2 * invN - mean * mean;
            float rstd = rsqrtf(var + 1e-5f);
            float s = gn_w[t] * rstd;
            ssv[t] = s;
            tlv[t] = gn_b[t] - mean * s;
        }
        __syncthreads();
        if (t < 128) {
            float v = b_in[t];
            const float* wr = w_in + t * 128;
#pragma unroll 8
            for (int k = 0; k < 128; ++k) v += wr[k] * tlv[k];
            vA[b * 128 + t] = v;
        }
        unsigned short* ab = Asb + b * 16384;
        const float4* w4 = (const float4*)w_in;
#pragma unroll
        for (int i = 0; i < 16; ++i) {
            int idx = t + i * 256;
            int c = idx >> 5, k4 = idx & 31;
            float4 w = w4[idx];
            ushort4 o;
            o.x = f2bf(w.x * ssv[k4 * 4 + 0]);
            o.y = f2bf(w.y * ssv[k4 * 4 + 1]);
            o.z = f2bf(w.z * ssv[k4 * 4 + 2]);
            o.w = f2bf(w.w * ssv[k4 * 4 + 3]);
            *(ushort4*)&ab[c * 128 + k4 * 4] = o;
        }
    }
    gsync(ctr + 1, nblk);

    // ---------- P2: GEMM1 (A=Asb global, B=Xt) -> acc1; scores -> Sg ----------
    if (t < 128) v_s[t] = vA[b * 128 + t];

    const unsigned short* ab = Asb + b * 16384;
    f32x4 acc1[2][8];
#pragma unroll
    for (int a = 0; a < 2; ++a)
#pragma unroll
        for (int pt = 0; pt < 8; ++pt) acc1[a][pt] = (f32x4){0.f, 0.f, 0.f, 0.f};

#pragma unroll
    for (int ks = 0; ks < 4; ++ks) {
        short8 a0 = *(const short8*)&ab[(wv * 32 + i16) * 128 + ks * 32 + q * 8];
        short8 a1 = *(const short8*)&ab[(wv * 32 + 16 + i16) * 128 + ks * 32 + q * 8];
        const int cb = ((ks * 4 + q) ^ i16) << 3;
#pragma unroll
        for (int pt = 0; pt < 8; ++pt) {
            short8 bb = *(const short8*)&Xt[(pt * 16 + i16) * 128 + cb];
            acc1[0][pt] = __builtin_amdgcn_mfma_f32_16x16x32_bf16(a0, bb, acc1[0][pt], 0, 0, 0);
            acc1[1][pt] = __builtin_amdgcn_mfma_f32_16x16x32_bf16(a1, bb, acc1[1][pt], 0, 0, 0);
        }
    }
    __syncthreads();           // Xt (x) dead; v_s ready

    // Hs[c][p] = h (+v), swizzled
#pragma unroll
    for (int a = 0; a < 2; ++a) {
        int cb0 = wv * 32 + a * 16 + q * 4;
#pragma unroll
        for (int pt = 0; pt < 8; ++pt) {
            int p = pt * 16 + i16;
#pragma unroll
            for (int r = 0; r < 4; ++r) {
                int c = cb0 + r;
                Xt[c * 128 + ((((p >> 3) ^ (c & 15)) << 3)) + (p & 7)] =
                    f2bf(acc1[a][pt][r] + v_s[c]);
            }
        }
    }
    __syncthreads();

#pragma unroll
    for (int hh = 0; hh < 2; ++hh) {
        int h = wv * 2 + hh;
        int row = (h * 16 + i16) * 128;
        f32x4 sacc = (f32x4){0.f, 0.f, 0.f, 0.f};
#pragma unroll
        for (int ks = 0; ks < 4; ++ks) {
            short8 f = *(const short8*)&Xt[row + (((ks * 4 + q) ^ i16) << 3)];
            sacc = __builtin_amdgcn_mfma_f32_16x16x32_bf16(f, f, sacc, 0, 0, 0);
        }
        float* sg = Sg + (b * 8 + h) * 256;
#pragma unroll
        for (int r = 0; r < 4; ++r)
            atomicAdd(&sg[(q * 4 + r) * 16 + i16], sacc[r]);
    }
    gsync(ctr + 2, nblk);

    // ---------- P3 (tile==0 only): softmax + w_eff(bf16) ----------
    if (tile == 0) {
        float* WF = (float*)Xt;            // 2048 floats, reuse LDS
        if (t < 128) {
            const float* row = Sg + b * 2048 + t * 16;
            float v[16];
            float m = -1e30f;
#pragma unroll
            for (int j = 0; j < 16; ++j) { v[j] = row[j] * 0.25f; m = fmaxf(m, v[j]); }
            float sum = 0.f;
#pragma unroll
            for (int j = 0; j < 16; ++j) { v[j] = __expf(v[j] - m); sum += v[j]; }
            float inv = 1.0f / sum;
#pragma unroll
            for (int j = 0; j < 16; ++j) WF[t * 16 + j] = v[j] * inv;
        }
        __syncthreads();
        unsigned short* wo = weffb + b * 16384;
#pragma unroll 2
        for (int n = 0; n < 64; ++n) {
            int idx = t + n * 256;
            int c = idx >> 7, k = idx & 127;
            int h = k >> 4, j = k & 15;
            const float* wr = w_out + c * 128 + h * 16;
            const float* Wr = WF + h * 256 + j;
            float a = 0.f;
#pragma unroll
            for (int i = 0; i < 16; ++i) a += wr[i] * Wr[i * 16];
            wo[idx] = f2bf(a);
        }
    }
    gsync(ctr + 3, nblk);

    // ---------- P4: h^T -> Xt, GEMM2, epilogue ----------
    if (t < 128) bo_s[t] = b_out[t];

    // h1^T[p][c] (= acc1 + v_s), swizzled
#pragma unroll
    for (int a = 0; a < 2; ++a) {
        int cb0 = wv * 32 + a * 16 + q * 4;
#pragma unroll
        for (int pt = 0; pt < 8; ++pt) {
            int p = pt * 16 + i16;
            int rb = p * 128;
            int sw = p & 15;
#pragma unroll
            for (int r = 0; r < 4; ++r) {
                int c = cb0 + r;
                Xt[rb + ((((c >> 3) ^ sw) << 3)) + (c & 7)] =
                    f2bf(acc1[a][pt][r] + v_s[c]);
            }
        }
    }
    __syncthreads();

    const unsigned short* ab2 = weffb + b * 16384;
    f32x4 acc2[2][8];
#pragma unroll
    for (int a = 0; a < 2; ++a)
#pragma unroll
        for (int pt = 0; pt < 8; ++pt) acc2[a][pt] = (f32x4){0.f, 0.f, 0.f, 0.f};

#pragma unroll
    for (int ks = 0; ks < 4; ++ks) {
        short8 a0 = *(const short8*)&ab2[(wv * 32 + i16) * 128 + ks * 32 + q * 8];
        short8 a1 = *(const short8*)&ab2[(wv * 32 + 16 + i16) * 128 + ks * 32 + q * 8];
        const int cb = ((ks * 4 + q) ^ i16) << 3;
#pragma unroll
        for (int pt = 0; pt < 8; ++pt) {
            short8 bb = *(const short8*)&Xt[(pt * 16 + i16) * 128 + cb];
            acc2[0][pt] = __builtin_amdgcn_mfma_f32_16x16x32_bf16(a0, bb, acc2[0][pt], 0, 0, 0);
            acc2[1][pt] = __builtin_amdgcn_mfma_f32_16x16x32_bf16(a1, bb, acc2[1][pt], 0, 0, 0);
        }
    }
    __syncthreads();

    // Hb[c][p] = acc2 + b_out, swizzled
#pragma unroll
    for (int a = 0; a < 2; ++a) {
        int cb0 = wv * 32 + a * 16 + q * 4;
#pragma unroll
        for (int pt = 0; pt < 8; ++pt) {
            int p = pt * 16 + i16;
#pragma unroll
            for (int r = 0; r < 4; ++r) {
                int c = cb0 + r;
                Xt[c * 128 + ((((p >> 3) ^ (c & 15)) << 3)) + (p & 7)] =
                    f2bf(acc2[a][pt][r] + bo_s[c]);
            }
        }
    }
    __syncthreads();

    // epilogue: out = x + h, float4 both ways
    float* ob = out + (size_t)b * (128 * NPOS) + p0;
#pragma unroll
    for (int i = 0; i < 16; ++i) {
        int idx = t + i * 256;
        int c = idx >> 5, p4 = idx & 31;
        int pcol = p4 * 4;
        ushort4 hv = *(const ushort4*)&Xt[c * 128 + ((((pcol >> 3) ^ (c & 15)) << 3)) + (pcol & 7)];
        const float4 xv = *(const float4*)&xb[(size_t)c * NPOS + pcol];
        float4 o;
        o.x = xv.x + bf2f(hv.x);
        o.y = xv.y + bf2f(hv.y);
        o.z = xv.z + bf2f(hv.z);
        o.w = xv.w + bf2f(hv.w);
        *(float4*)&ob[(size_t)c * NPOS + pcol] = o;
    }
}

extern "C" void kernel_launch(void* const* d_in, const int* in_sizes, int n_in,
                              void* d_out, int out_size, void* d_ws, size_t ws_size,
                              hipStream_t stream) {
    const float* x    = (const float*)d_in[0];
    const float* gn_w = (const float*)d_in[1];
    const float* gn_b = (const float*)d_in[2];
    const float* w_in = (const float*)d_in[3];
    const float* b_in = (const float*)d_in[4];
    const float* w_out= (const float*)d_in[5];
    const float* b_out= (const float*)d_in[6];
    float* out = (float*)d_out;

    float* ws = (float*)d_ws;
    unsigned* ctr = (unsigned*)ws;                            // 16 slots
    float* stats  = ws + 16;                                  // 128 f
    float* Sg     = ws + 144;                                 // 16384 f
    float* vA     = ws + 16528;                               // 1024 f
    unsigned short* Asb   = (unsigned short*)(ws + 17552);    // 131072 us
    unsigned short* weffb = (unsigned short*)(ws + 83088);    // 131072 us

    hipMemsetAsync(d_ws, 0, (16 + 128 + 16384) * sizeof(float), stream);
    k_fused<<<dim3(1024), dim3(256), 0, stream>>>(
        x, gn_w, gn_b, w_in, b_in, w_out, b_out, out,
        ctr, stats, Sg, vA, Asb, weffb);
}

// Round 5
// 210.048 us; speedup vs baseline: 5.0463x; 5.0463x over previous
//
#include <hip/hip_runtime.h>

// AttentionBlock: B=8, C=128, H=W=128, GROUPS=8, HEADS=8, HEAD_DIM=16
// R5: revert R4 fusion (grid barriers -> L2 invalidation storms, 955us).
// R2 recompute structure + latency fixes:
//  - 64-pos tiles, 2048 blocks, LDS ~17KB -> 8 blocks/CU (K2) / 6 (K4)
//  - XOR swizzle (chunk ^ row&15) -> conflict-free ds_write_b128/ds_read_b128
//  - no h1t cache (R3 showed recompute wins); K4 redoes GEMM1 then GEMM2
// Pipeline: stats -> prep(fold GN into w_in, bf16) -> gemm1+scores ->
//           softmax+w_eff(bf16) -> gemm1+gemm2+residual

#define NPOS 16384

typedef short short8 __attribute__((ext_vector_type(8)));   // 8 bf16
typedef float f32x4 __attribute__((ext_vector_type(4)));

__device__ __forceinline__ unsigned short f2bf(float f) {
    union { float f; unsigned u; } v; v.f = f;
    unsigned r = (v.u + 0x7fffu + ((v.u >> 16) & 1u)) >> 16;
    return (unsigned short)r;
}
__device__ __forceinline__ float bf2f(unsigned short h) {
    union { unsigned u; float f; } v; v.u = ((unsigned)h) << 16;
    return v.f;
}

// ---------------- K1: per-(b,g) sum / sumsq ----------------
__global__ __launch_bounds__(256) void k_stats(const float* __restrict__ x,
                                               float* __restrict__ stats) {
    const float4* p = (const float4*)(x + (size_t)blockIdx.x * 16384);
    int t = threadIdx.x;
    float s1 = 0.f, s2 = 0.f;
#pragma unroll
    for (int j = 0; j < 16; ++j) {
        float4 v = p[t + j * 256];
        s1 += v.x + v.y + v.z + v.w;
        s2 += v.x * v.x + v.y * v.y + v.z * v.z + v.w * v.w;
    }
    for (int off = 32; off; off >>= 1) {
        s1 += __shfl_down(s1, off);
        s2 += __shfl_down(s2, off);
    }
    __shared__ float r1[4], r2[4];
    int wv = t >> 6;
    if ((t & 63) == 0) { r1[wv] = s1; r2[wv] = s2; }
    __syncthreads();
    if (t == 0) {
        s1 = r1[0] + r1[1] + r1[2] + r1[3];
        s2 = r2[0] + r2[1] + r2[2] + r2[3];
        int bg = blockIdx.x >> 4;
        atomicAdd(&stats[bg * 2 + 0], s1);
        atomicAdd(&stats[bg * 2 + 1], s2);
    }
}

// ---------------- K1b: s,v and Asb = bf16(w_in * s) ----------------
__global__ __launch_bounds__(256) void k_prep(const float* __restrict__ stats,
                                              const float* __restrict__ gn_w,
                                              const float* __restrict__ gn_b,
                                              const float* __restrict__ w_in,
                                              const float* __restrict__ b_in,
                                              float* __restrict__ vA,
                                              unsigned short* __restrict__ Asb) {
    int b = blockIdx.x, t = threadIdx.x;
    __shared__ float ss[128], tl[128];
    if (t < 128) {
        int g = t >> 4;
        float s1 = stats[(b * 8 + g) * 2 + 0];
        float s2 = stats[(b * 8 + g) * 2 + 1];
        const float invN = 1.0f / 262144.0f;
        float mean = s1 * invN;
        float var = s2 * invN - mean * mean;
        float rstd = rsqrtf(var + 1e-5f);
        float s = gn_w[t] * rstd;
        ss[t] = s;
        tl[t] = gn_b[t] - mean * s;
    }
    __syncthreads();
    if (t < 128) {
        float v = b_in[t];
        const float* wr = w_in + t * 128;
#pragma unroll 8
        for (int k = 0; k < 128; ++k) v += wr[k] * tl[k];
        vA[b * 128 + t] = v;
    }
    unsigned short* ab = Asb + b * 16384;
    const float4* w4 = (const float4*)w_in;
#pragma unroll
    for (int i = 0; i < 16; ++i) {
        int idx = t + i * 256;
        int c = idx >> 5, k4 = idx & 31;
        float4 w = w4[idx];
        ushort4 o;
        o.x = f2bf(w.x * ss[k4 * 4 + 0]);
        o.y = f2bf(w.y * ss[k4 * 4 + 1]);
        o.z = f2bf(w.z * ss[k4 * 4 + 2]);
        o.w = f2bf(w.w * ss[k4 * 4 + 3]);
        *(ushort4*)&ab[c * 128 + k4 * 4] = o;
    }
}

// ---------------- K2: GEMM1 + partial scores (64-pos tiles) ----------------
__global__ __launch_bounds__(256, 8) void k_gemm1_scores(const float* __restrict__ x,
                                                         const unsigned short* __restrict__ Asb,
                                                         const float* __restrict__ vA,
                                                         float* __restrict__ Sg) {
    __shared__ unsigned short Xt[64 * 128];   // 16KB: [p][k] swizzled, then [c][p] swizzled
    __shared__ float v_s[128];

    const int t = threadIdx.x;
    const int lane = t & 63, wv = t >> 6;
    const int q = lane >> 4, i16 = lane & 15;
    const int b = blockIdx.x >> 8;
    const int p0 = (blockIdx.x & 255) << 6;
    const float* xb = x + (size_t)b * (128 * NPOS) + p0;

    if (t < 128) v_s[t] = vA[b * 128 + t];

    // stage Xt[p][k] = bf16(x[k][p0+p]); chunk c8 at (c8 ^ (p&15))
    {
        const int p = t & 63;
        const int sw = p & 15;
        const int kq0 = t >> 6;
#pragma unroll
        for (int i = 0; i < 4; ++i) {
            int kq = kq0 + i * 4;
            const float* col = xb + (size_t)(kq * 8) * NPOS + p;
            short8 o;
#pragma unroll
            for (int e = 0; e < 8; ++e)
                ((unsigned short*)&o)[e] = f2bf(col[(size_t)e * NPOS]);
            *(short8*)&Xt[p * 128 + ((kq ^ sw) << 3)] = o;
        }
    }
    __syncthreads();

    const unsigned short* ab = Asb + b * 16384;
    f32x4 acc[2][4];
#pragma unroll
    for (int a = 0; a < 2; ++a)
#pragma unroll
        for (int pt = 0; pt < 4; ++pt) acc[a][pt] = (f32x4){0.f, 0.f, 0.f, 0.f};

#pragma unroll
    for (int ks = 0; ks < 4; ++ks) {
        short8 a0 = *(const short8*)&ab[(wv * 32 + i16) * 128 + ks * 32 + q * 8];
        short8 a1 = *(const short8*)&ab[(wv * 32 + 16 + i16) * 128 + ks * 32 + q * 8];
        const int cb = ((ks * 4 + q) ^ i16) << 3;
#pragma unroll
        for (int pt = 0; pt < 4; ++pt) {
            short8 bb = *(const short8*)&Xt[(pt * 16 + i16) * 128 + cb];
            acc[0][pt] = __builtin_amdgcn_mfma_f32_16x16x32_bf16(a0, bb, acc[0][pt], 0, 0, 0);
            acc[1][pt] = __builtin_amdgcn_mfma_f32_16x16x32_bf16(a1, bb, acc[1][pt], 0, 0, 0);
        }
    }
    __syncthreads();            // Xt(x) dead -> reuse as Hs[c][p] (rows 128B)

    // Hs[c][p] = h1 (+v), p-chunk swizzle: (p>>3) ^ (c&7)
#pragma unroll
    for (int a = 0; a < 2; ++a) {
        int cb0 = wv * 32 + a * 16 + q * 4;
#pragma unroll
        for (int pt = 0; pt < 4; ++pt) {
            int p = pt * 16 + i16;
#pragma unroll
            for (int r = 0; r < 4; ++r) {
                int c = cb0 + r;
                Xt[c * 64 + ((((p >> 3) ^ (c & 7)) << 3)) + (p & 7)] =
                    f2bf(acc[a][pt][r] + v_s[c]);
            }
        }
    }
    __syncthreads();

    // scores: wave wv -> heads 2wv, 2wv+1; A==B frag (H H^T over this tile's 64 p)
#pragma unroll
    for (int hh = 0; hh < 2; ++hh) {
        int h = wv * 2 + hh;
        int row = (h * 16 + i16) * 64;
        int sw = i16 & 7;
        f32x4 sacc = (f32x4){0.f, 0.f, 0.f, 0.f};
#pragma unroll
        for (int ks = 0; ks < 2; ++ks) {
            short8 f = *(const short8*)&Xt[row + (((ks * 4 + q) ^ sw) << 3)];
            sacc = __builtin_amdgcn_mfma_f32_16x16x32_bf16(f, f, sacc, 0, 0, 0);
        }
        float* sg = Sg + (b * 8 + h) * 256;
#pragma unroll
        for (int r = 0; r < 4; ++r)
            atomicAdd(&sg[(q * 4 + r) * 16 + i16], sacc[r]);
    }
}

// ---------------- K3: softmax + w_eff (bf16) ----------------
__global__ __launch_bounds__(256) void k_softmax_weff(const float* __restrict__ Sg,
                                                      const float* __restrict__ w_out,
                                                      unsigned short* __restrict__ weffb) {
    int b = blockIdx.x, t = threadIdx.x;
    __shared__ float W[2048];
    if (t < 128) {
        const float* row = Sg + b * 2048 + t * 16;
        float v[16];
        float m = -1e30f;
#pragma unroll
        for (int j = 0; j < 16; ++j) { v[j] = row[j] * 0.25f; m = fmaxf(m, v[j]); }
        float sum = 0.f;
#pragma unroll
        for (int j = 0; j < 16; ++j) { v[j] = __expf(v[j] - m); sum += v[j]; }
        float inv = 1.0f / sum;
#pragma unroll
        for (int j = 0; j < 16; ++j) W[t * 16 + j] = v[j] * inv;
    }
    __syncthreads();
    unsigned short* wo = weffb + b * 16384;
#pragma unroll 2
    for (int n = 0; n < 64; ++n) {
        int idx = t + n * 256;
        int c = idx >> 7, k = idx & 127;
        int h = k >> 4, j = k & 15;
        const float* wr = w_out + c * 128 + h * 16;
        const float* Wr = W + h * 256 + j;
        float a = 0.f;
#pragma unroll
        for (int i = 0; i < 16; ++i) a += wr[i] * Wr[i * 16];
        wo[idx] = f2bf(a);
    }
}

// ---------------- K4: recompute GEMM1, GEMM2, out = x + b_out + w_eff@h1 ----------------
__global__ __launch_bounds__(256, 6) void k_attn_out(const float* __restrict__ x,
                                                     const unsigned short* __restrict__ Asb,
                                                     const float* __restrict__ vA,
                                                     const unsigned short* __restrict__ weffb,
                                                     const float* __restrict__ b_out,
                                                     float* __restrict__ out) {
    __shared__ unsigned short Xt[64 * 128];   // x^T -> h1^T -> h(+b_out)
    __shared__ float v_s[128];
    __shared__ float bo_s[128];

    const int t = threadIdx.x;
    const int lane = t & 63, wv = t >> 6;
    const int q = lane >> 4, i16 = lane & 15;
    const int b = blockIdx.x >> 8;
    const int p0 = (blockIdx.x & 255) << 6;
    const float* xb = x + (size_t)b * (128 * NPOS) + p0;

    if (t < 128) { v_s[t] = vA[b * 128 + t]; bo_s[t] = b_out[t]; }

    // stage Xt[p][k] = bf16(x[k][p0+p])
    {
        const int p = t & 63;
        const int sw = p & 15;
        const int kq0 = t >> 6;
#pragma unroll
        for (int i = 0; i < 4; ++i) {
            int kq = kq0 + i * 4;
            const float* col = xb + (size_t)(kq * 8) * NPOS + p;
            short8 o;
#pragma unroll
            for (int e = 0; e < 8; ++e)
                ((unsigned short*)&o)[e] = f2bf(col[(size_t)e * NPOS]);
            *(short8*)&Xt[p * 128 + ((kq ^ sw) << 3)] = o;
        }
    }
    __syncthreads();

    // GEMM1
    const unsigned short* ab = Asb + b * 16384;
    f32x4 acc1[2][4];
#pragma unroll
    for (int a = 0; a < 2; ++a)
#pragma unroll
        for (int pt = 0; pt < 4; ++pt) acc1[a][pt] = (f32x4){0.f, 0.f, 0.f, 0.f};

#pragma unroll
    for (int ks = 0; ks < 4; ++ks) {
        short8 a0 = *(const short8*)&ab[(wv * 32 + i16) * 128 + ks * 32 + q * 8];
        short8 a1 = *(const short8*)&ab[(wv * 32 + 16 + i16) * 128 + ks * 32 + q * 8];
        const int cb = ((ks * 4 + q) ^ i16) << 3;
#pragma unroll
        for (int pt = 0; pt < 4; ++pt) {
            short8 bb = *(const short8*)&Xt[(pt * 16 + i16) * 128 + cb];
            acc1[0][pt] = __builtin_amdgcn_mfma_f32_16x16x32_bf16(a0, bb, acc1[0][pt], 0, 0, 0);
            acc1[1][pt] = __builtin_amdgcn_mfma_f32_16x16x32_bf16(a1, bb, acc1[1][pt], 0, 0, 0);
        }
    }
    __syncthreads();   // x-stage dead

    // h1^T -> Xt[p][c] (+v), chunk swizzle (c>>3) ^ (p&15)
#pragma unroll
    for (int a = 0; a < 2; ++a) {
        int cb0 = wv * 32 + a * 16 + q * 4;
#pragma unroll
        for (int pt = 0; pt < 4; ++pt) {
            int p = pt * 16 + i16;
#pragma unroll
            for (int r = 0; r < 4; ++r) {
                int c = cb0 + r;
                Xt[p * 128 + ((((c >> 3) ^ i16) << 3)) + (c & 7)] =
                    f2bf(acc1[a][pt][r] + v_s[c]);
            }
        }
    }
    __syncthreads();

    // GEMM2: A = weff (global bf16), B = h1^T (LDS)
    const unsigned short* ab2 = weffb + b * 16384;
    f32x4 acc2[2][4];
#pragma unroll
    for (int a = 0; a < 2; ++a)
#pragma unroll
        for (int pt = 0; pt < 4; ++pt) acc2[a][pt] = (f32x4){0.f, 0.f, 0.f, 0.f};

#pragma unroll
    for (int ks = 0; ks < 4; ++ks) {
        short8 a0 = *(const short8*)&ab2[(wv * 32 + i16) * 128 + ks * 32 + q * 8];
        short8 a1 = *(const short8*)&ab2[(wv * 32 + 16 + i16) * 128 + ks * 32 + q * 8];
        const int cb = ((ks * 4 + q) ^ i16) << 3;
#pragma unroll
        for (int pt = 0; pt < 4; ++pt) {
            short8 bb = *(const short8*)&Xt[(pt * 16 + i16) * 128 + cb];
            acc2[0][pt] = __builtin_amdgcn_mfma_f32_16x16x32_bf16(a0, bb, acc2[0][pt], 0, 0, 0);
            acc2[1][pt] = __builtin_amdgcn_mfma_f32_16x16x32_bf16(a1, bb, acc2[1][pt], 0, 0, 0);
        }
    }
    __syncthreads();

    // Hb[c][p] = acc2 + b_out, p-chunk swizzle (p>>3) ^ (c&7)
#pragma unroll
    for (int a = 0; a < 2; ++a) {
        int cb0 = wv * 32 + a * 16 + q * 4;
#pragma unroll
        for (int pt = 0; pt < 4; ++pt) {
            int p = pt * 16 + i16;
#pragma unroll
            for (int r = 0; r < 4; ++r) {
                int c = cb0 + r;
                Xt[c * 64 + ((((p >> 3) ^ (c & 7)) << 3)) + (p & 7)] =
                    f2bf(acc2[a][pt][r] + bo_s[c]);
            }
        }
    }
    __syncthreads();

    // epilogue: out = x + h, float4 both ways
    float* ob = out + (size_t)b * (128 * NPOS) + p0;
#pragma unroll
    for (int i = 0; i < 8; ++i) {
        int idx = t + i * 256;               // 2048 float4 chunks (128c x 16)
        int c = idx >> 4, pc4 = idx & 15;
        int p = pc4 * 4;
        ushort4 hv = *(const ushort4*)&Xt[c * 64 + ((((p >> 3) ^ (c & 7)) << 3)) + (p & 7)];
        const float4 xv = *(const float4*)&xb[(size_t)c * NPOS + p];
        float4 o;
        o.x = xv.x + bf2f(hv.x);
        o.y = xv.y + bf2f(hv.y);
        o.z = xv.z + bf2f(hv.z);
        o.w = xv.w + bf2f(hv.w);
        *(float4*)&ob[(size_t)c * NPOS + p] = o;
    }
}

extern "C" void kernel_launch(void* const* d_in, const int* in_sizes, int n_in,
                              void* d_out, int out_size, void* d_ws, size_t ws_size,
                              hipStream_t stream) {
    const float* x    = (const float*)d_in[0];
    const float* gn_w = (const float*)d_in[1];
    const float* gn_b = (const float*)d_in[2];
    const float* w_in = (const float*)d_in[3];
    const float* b_in = (const float*)d_in[4];
    const float* w_out= (const float*)d_in[5];
    const float* b_out= (const float*)d_in[6];
    float* out = (float*)d_out;

    float* ws    = (float*)d_ws;
    float* stats = ws;                                        // 128 f
    float* Sg    = ws + 128;                                  // 16384 f
    float* vA    = ws + 16512;                                // 1024 f
    unsigned short* Asb   = (unsigned short*)(ws + 17536);    // 131072 us
    unsigned short* weffb = (unsigned short*)(ws + 83072);    // 131072 us

    hipMemsetAsync(d_ws, 0, (128 + 16384) * sizeof(float), stream);
    k_stats<<<dim3(1024), dim3(256), 0, stream>>>(x, stats);
    k_prep<<<dim3(8), dim3(256), 0, stream>>>(stats, gn_w, gn_b, w_in, b_in, vA, Asb);
    k_gemm1_scores<<<dim3(2048), dim3(256), 0, stream>>>(x, Asb, vA, Sg);
    k_softmax_weff<<<dim3(8), dim3(256), 0, stream>>>(Sg, w_out, weffb);
    k_attn_out<<<dim3(2048), dim3(256), 0, stream>>>(x, Asb, vA, weffb, b_out, out);
}